// Round 1
// baseline (506.197 us; speedup 1.0000x reference)
//
#include <hip/hip_runtime.h>
#include <cstdint>

#define S_LEN 2048
#define B_SZ 8
#define D_DIM 2048
#define M_DIM (S_LEN * B_SZ)   // 16384 tokens
#define CHAINS (B_SZ * D_DIM)  // 16384 scan chains
#define BK 64
#define KTILES (D_DIM / BK)    // 32

typedef __bf16 bf16;
typedef bf16 bf16x8 __attribute__((ext_vector_type(8)));
typedef bf16 bf16x4 __attribute__((ext_vector_type(4)));
typedef float f32x4 __attribute__((ext_vector_type(4)));

// ---------------- async global->LDS (16B, wave-uniform LDS base + lane*16) ----
__device__ __forceinline__ void async_copy16(void* lds, const void* g) {
    __builtin_amdgcn_global_load_lds(
        (const __attribute__((address_space(1))) unsigned int*)g,
        (__attribute__((address_space(3))) unsigned int*)lds,
        16, 0, 0);
}

// ---------------- fp32 -> bf16 conversion of x, W_x, W_a ---------------------
__global__ void k_convert(const float4* __restrict__ x,
                          const float4* __restrict__ wx,
                          const float4* __restrict__ wa,
                          bf16* __restrict__ xb,
                          bf16* __restrict__ wxb,
                          bf16* __restrict__ wab) {
    const long NX4 = (long)M_DIM * D_DIM / 4;   // 8388608
    const long NW4 = (long)D_DIM * D_DIM / 4;   // 1048576
    const long total = NX4 + 2 * NW4;
    for (long i = (long)blockIdx.x * blockDim.x + threadIdx.x; i < total;
         i += (long)gridDim.x * blockDim.x) {
        const float4* s; bf16* d; long k;
        if (i < NX4)            { s = x;  d = xb;  k = i; }
        else if (i < NX4 + NW4) { s = wx; d = wxb; k = i - NX4; }
        else                    { s = wa; d = wab; k = i - NX4 - NW4; }
        float4 v = s[k];
        bf16x4 o;
        o[0] = (bf16)v.x; o[1] = (bf16)v.y; o[2] = (bf16)v.z; o[3] = (bf16)v.w;
        *reinterpret_cast<bf16x4*>(d + 4 * k) = o;
    }
}

// ---------------- cvec[e] = -C * softplus(a_param[e]) ------------------------
__global__ void k_cvec(const float* __restrict__ ap, float* __restrict__ cv) {
    int e = blockIdx.x * blockDim.x + threadIdx.x;
    if (e < D_DIM) {
        float v = ap[e];
        cv[e] = -8.0f * log1pf(expf(v));
    }
}

// ---------------- fused dual-GEMM + gate epilogue ----------------------------
// out per (token m, channel e):
//   zx = x@Wx^T + bx ; za = x@Wa^T + ba
//   gx = sigmoid(zx); ga = sigmoid(za); la = cv[e]*ga; a = exp(la)
//   mult = sqrt(1-a*a);  (s==0: a=0, mult=1)
//   abuf[m][e] = a ; y[m][e] = x[m][e]*gx*mult
__global__ __launch_bounds__(256, 2) void k_gemm(
    const bf16* __restrict__ xb,    // [M][D] bf16
    const bf16* __restrict__ wxb,   // [D][D] bf16 (row e, col d)
    const bf16* __restrict__ wab,   // [D][D] bf16
    const float* __restrict__ x32,  // original x fp32
    const float* __restrict__ bx,
    const float* __restrict__ ba,
    const float* __restrict__ cv,
    float* __restrict__ abuf,       // [M][D] fp32
    float* __restrict__ y)          // [M][D] fp32 (normed_x staged here)
{
    // LDS: A tile 128x64 bf16 (16KB) | Bx 128x64 (16KB) | Ba 128x64 (16KB)
    __shared__ __align__(16) char smem[48 * 1024];
    char* sA  = smem;
    char* sBx = smem + 16384;
    char* sBa = smem + 32768;

    const int tid  = threadIdx.x;
    const int lane = tid & 63;
    const int w    = tid >> 6;       // 4 waves
    const int wr   = w >> 1;         // wave row 0..1 (64 rows each)
    const int wc   = w & 1;          // wave col 0..1 (64 cols each)
    const int m0 = blockIdx.y * 128;
    const int e0 = blockIdx.x * 128;

    f32x4 accx[4][4];
    f32x4 acca[4][4];
#pragma unroll
    for (int i = 0; i < 4; ++i)
#pragma unroll
        for (int j = 0; j < 4; ++j) {
            accx[i][j] = (f32x4)(0.0f);
            acca[i][j] = (f32x4)(0.0f);
        }

    // staging geometry: one instr = 1KB = 8 rows of 128B. lane -> (row, chunk)
    const int srow   = lane >> 3;    // 0..7
    const int schunk = lane & 7;     // 16B chunk within row

    for (int kt = 0; kt < KTILES; ++kt) {
        const long kcolb = (long)kt * (BK * 2);  // 128B per K-tile within a row

        // ---- stage A, Bx, Ba (each: 4 waves x 4 instr x 1KB = 16KB) ----
#pragma unroll
        for (int j = 0; j < 4; ++j) {
            const int baseRow = (w * 4 + j) * 8;
            const int row = baseRow + srow;
            const int swz = schunk ^ (row & 7);  // inverse-swizzled global src
            const long rowbyA = (long)(m0 + row) * (D_DIM * 2) + kcolb + swz * 16;
            async_copy16(sA + baseRow * 128, (const char*)xb + rowbyA);
            const long rowbyB = (long)(e0 + row) * (D_DIM * 2) + kcolb + swz * 16;
            async_copy16(sBx + baseRow * 128, (const char*)wxb + rowbyB);
            async_copy16(sBa + baseRow * 128, (const char*)wab + rowbyB);
        }
        __syncthreads();   // compiler drains vmcnt(0) before s_barrier

        // ---- compute: 2 k-steps of 16x16x32, 4x4 frags, both matrices ----
#pragma unroll
        for (int ks = 0; ks < 2; ++ks) {
            const int kchunk = ks * 4 + (lane >> 4);  // 16B chunk idx along K
            bf16x8 af[4], bxf[4], baf[4];
#pragma unroll
            for (int i = 0; i < 4; ++i) {
                const int r = wr * 64 + i * 16 + (lane & 15);
                const int pc = kchunk ^ (r & 7);      // swizzled read
                af[i] = *reinterpret_cast<const bf16x8*>(sA + r * 128 + pc * 16);
            }
#pragma unroll
            for (int j = 0; j < 4; ++j) {
                const int r = wc * 64 + j * 16 + (lane & 15);
                const int pc = kchunk ^ (r & 7);
                bxf[j] = *reinterpret_cast<const bf16x8*>(sBx + r * 128 + pc * 16);
                baf[j] = *reinterpret_cast<const bf16x8*>(sBa + r * 128 + pc * 16);
            }
#pragma unroll
            for (int i = 0; i < 4; ++i)
#pragma unroll
                for (int j = 0; j < 4; ++j) {
                    accx[i][j] = __builtin_amdgcn_mfma_f32_16x16x32_bf16(
                        af[i], bxf[j], accx[i][j], 0, 0, 0);
                    acca[i][j] = __builtin_amdgcn_mfma_f32_16x16x32_bf16(
                        af[i], baf[j], acca[i][j], 0, 0, 0);
                }
        }
        __syncthreads();  // protect LDS before next iteration's staging
    }

    // ---- epilogue: gates + a + normed_x ----
    const int colL = lane & 15;
    const int rgrp = lane >> 4;
#pragma unroll
    for (int j = 0; j < 4; ++j) {
        const int e = e0 + wc * 64 + j * 16 + colL;
        const float bxv = bx[e];
        const float bav = ba[e];
        const float cvv = cv[e];
#pragma unroll
        for (int i = 0; i < 4; ++i) {
            const int mbase = m0 + wr * 64 + i * 16 + rgrp * 4;
#pragma unroll
            for (int r = 0; r < 4; ++r) {
                const int m = mbase + r;
                const float zx = accx[i][j][r] + bxv;
                const float za = acca[i][j][r] + bav;
                const float gx = 1.0f / (1.0f + __expf(-zx));
                const float ga = 1.0f / (1.0f + __expf(-za));
                const float la = cvv * ga;
                float a = __expf(la);
                float mult = sqrtf(fmaxf(1.0f - a * a, 0.0f));
                if (m < B_SZ) { a = 0.0f; mult = 1.0f; }  // s == 0 reset
                const long o = (long)m * D_DIM + e;
                const float xv = x32[o];
                abuf[o] = a;
                y[o] = xv * gx * mult;
            }
        }
    }
}

// ---------------- in-place scan over S: h = a*h + xn, y <- h -----------------
__global__ __launch_bounds__(64) void k_scan(
    const float* __restrict__ abuf,
    float* __restrict__ y,           // contains xn; overwritten with h states
    const float* __restrict__ h0,
    float* __restrict__ hn) {
    const int c = blockIdx.x * 64 + threadIdx.x;  // chain id, 0..16383
    float h = h0[c];

    float av0[16], xv0[16], av1[16], xv1[16];
    // prologue: load group 0
#pragma unroll
    for (int j = 0; j < 16; ++j) {
        const long o = (long)j * CHAINS + c;
        av0[j] = abuf[o];
        xv0[j] = y[o];
    }
    // 128 groups of 16 steps, ping-pong double-buffer (static indexing only)
    for (int g = 0; g < 128; g += 2) {
        const long base1 = ((long)(g + 1) * 16) * CHAINS + c;
        if (g + 1 < 128) {
#pragma unroll
            for (int j = 0; j < 16; ++j) {
                av1[j] = abuf[base1 + (long)j * CHAINS];
                xv1[j] = y[base1 + (long)j * CHAINS];
            }
        }
        const long base0 = ((long)g * 16) * CHAINS + c;
#pragma unroll
        for (int j = 0; j < 16; ++j) {
            h = fmaf(av0[j], h, xv0[j]);
            y[base0 + (long)j * CHAINS] = h;
        }
        const long base2 = ((long)(g + 2) * 16) * CHAINS + c;
        if (g + 2 < 128) {
#pragma unroll
            for (int j = 0; j < 16; ++j) {
                av0[j] = abuf[base2 + (long)j * CHAINS];
                xv0[j] = y[base2 + (long)j * CHAINS];
            }
        }
        if (g + 1 < 128) {
#pragma unroll
            for (int j = 0; j < 16; ++j) {
                h = fmaf(av1[j], h, xv1[j]);
                y[base1 + (long)j * CHAINS] = h;
            }
        }
    }
    hn[c] = h;
}

// ---------------- launch -----------------------------------------------------
extern "C" void kernel_launch(void* const* d_in, const int* in_sizes, int n_in,
                              void* d_out, int out_size, void* d_ws, size_t ws_size,
                              hipStream_t stream) {
    const float* x  = (const float*)d_in[0];
    const float* h0 = (const float*)d_in[1];
    const float* Wx = (const float*)d_in[2];
    const float* bx = (const float*)d_in[3];
    const float* Wa = (const float*)d_in[4];
    const float* ba = (const float*)d_in[5];
    const float* ap = (const float*)d_in[6];
    float* out = (float*)d_out;

    char* ws = (char*)d_ws;
    // ws layout (bytes):
    //   xb  : 0                (M*D bf16 = 64MiB)
    //   wxb : 67108864         (8MiB)
    //   wab : 75497472         (8MiB)
    //   cv  : 83886080         (8KiB)
    //   abuf: 83894272         (M*D fp32 = 128MiB)   total ~208MiB
    bf16*  xb   = (bf16*)(ws);
    bf16*  wxb  = (bf16*)(ws + 67108864L);
    bf16*  wab  = (bf16*)(ws + 75497472L);
    float* cv   = (float*)(ws + 83886080L);
    float* abuf = (float*)(ws + 83894272L);

    float* y  = out;                         // S*B*D
    float* hn = out + (long)M_DIM * D_DIM;   // B*D

    k_convert<<<dim3(2048), dim3(256), 0, stream>>>(
        (const float4*)x, (const float4*)Wx, (const float4*)Wa, xb, wxb, wab);
    k_cvec<<<dim3(8), dim3(256), 0, stream>>>(ap, cv);
    k_gemm<<<dim3(D_DIM / 128, M_DIM / 128), dim3(256), 0, stream>>>(
        xb, wxb, wab, x, bx, ba, cv, abuf, y);
    k_scan<<<dim3(CHAINS / 64), dim3(64), 0, stream>>>(abuf, y, h0, hn);
}

// Round 2
// 486.191 us; speedup vs baseline: 1.0411x; 1.0411x over previous
//
#include <hip/hip_runtime.h>
#include <cstdint>

#define S_LEN 2048
#define B_SZ 8
#define D_DIM 2048
#define M_DIM (S_LEN * B_SZ)   // 16384 tokens
#define CHAINS (B_SZ * D_DIM)  // 16384 scan chains
#define BK 64
#define KTILES (D_DIM / BK)    // 32

typedef __bf16 bf16;
typedef bf16 bf16x8 __attribute__((ext_vector_type(8)));
typedef bf16 bf16x4 __attribute__((ext_vector_type(4)));
typedef float f32x4 __attribute__((ext_vector_type(4)));

// ---------------- async global->LDS (16B, wave-uniform LDS base + lane*16) ----
__device__ __forceinline__ void async_copy16(void* lds, const void* g) {
    __builtin_amdgcn_global_load_lds(
        (const __attribute__((address_space(1))) unsigned int*)g,
        (__attribute__((address_space(3))) unsigned int*)lds,
        16, 0, 0);
}

// ---------------- fp32 -> bf16 conversion of x, W_x, W_a ---------------------
__global__ void k_convert(const float4* __restrict__ x,
                          const float4* __restrict__ wx,
                          const float4* __restrict__ wa,
                          bf16* __restrict__ xb,
                          bf16* __restrict__ wxb,
                          bf16* __restrict__ wab) {
    const long NX4 = (long)M_DIM * D_DIM / 4;   // 8388608
    const long NW4 = (long)D_DIM * D_DIM / 4;   // 1048576
    const long total = NX4 + 2 * NW4;
    for (long i = (long)blockIdx.x * blockDim.x + threadIdx.x; i < total;
         i += (long)gridDim.x * blockDim.x) {
        const float4* s; bf16* d; long k;
        if (i < NX4)            { s = x;  d = xb;  k = i; }
        else if (i < NX4 + NW4) { s = wx; d = wxb; k = i - NX4; }
        else                    { s = wa; d = wab; k = i - NX4 - NW4; }
        float4 v = s[k];
        bf16x4 o;
        o[0] = (bf16)v.x; o[1] = (bf16)v.y; o[2] = (bf16)v.z; o[3] = (bf16)v.w;
        *reinterpret_cast<bf16x4*>(d + 4 * k) = o;
    }
}

// ---------------- cvec[e] = -C * softplus(a_param[e]) ------------------------
__global__ void k_cvec(const float* __restrict__ ap, float* __restrict__ cv) {
    int e = blockIdx.x * blockDim.x + threadIdx.x;
    if (e < D_DIM) {
        float v = ap[e];
        cv[e] = -8.0f * log1pf(expf(v));
    }
}

// ---------------- fused dual-GEMM + gate epilogue, 4-phase dbuf schedule -----
// Tile: BM=256 (tokens) x BN=128 (channels) x BK=64, 8 waves (4M x 2N).
// Per wave: 64x64 output per gate. LDS: 2 buffers x (A 32KB | Bx 16KB | Ba 16KB).
__global__ __launch_bounds__(512, 2) void k_gemm(
    const bf16* __restrict__ xb,    // [M][D] bf16
    const bf16* __restrict__ wxb,   // [D][D] bf16 (row e, col d)
    const bf16* __restrict__ wab,   // [D][D] bf16
    const float* __restrict__ x32,  // original x fp32
    const float* __restrict__ bx,
    const float* __restrict__ ba,
    const float* __restrict__ cv,
    float* __restrict__ abuf,       // [M][D] fp32
    float* __restrict__ y)          // [M][D] fp32 (normed_x staged here)
{
    __shared__ __align__(16) char smem[131072];  // 2 x 64KB buffers

    const int tid  = threadIdx.x;
    const int lane = tid & 63;
    const int w    = tid >> 6;       // 8 waves
    const int wm   = w >> 1;         // 0..3 (64 rows each)
    const int wn   = w & 1;          // 0..1 (64 cols each)

    // XCD-bijective swizzle: 1024 wgs = 8 xcds x 128 contiguous
    const int orig = blockIdx.x;
    const int wgid = (orig & 7) * 128 + (orig >> 3);
    const int m0 = (wgid >> 4) * 256;   // 64 M-blocks
    const int e0 = (wgid & 15) * 128;   // 16 N-blocks

    // staging geometry: one instr = 1KB = 8 rows of 128B
    const int srow  = lane >> 3;               // 0..7
    const int swz16 = ((lane & 7) ^ srow) * 16;  // inverse-swizzled src chunk

    const char* gA  = (const char*)xb;
    const char* gBx = (const char*)wxb;
    const char* gBa = (const char*)wab;

#define STAGE_A(buf, kt, p) do {                                               \
    const long kb_ = (long)(kt) * 128 + swz16;                                 \
    _Pragma("unroll")                                                          \
    for (int j_ = 0; j_ < 2; ++j_) {                                           \
        const int br_ = w * 32 + ((p) * 2 + j_) * 8;                           \
        async_copy16(smem + (buf) * 65536 + br_ * 128,                         \
                     gA + ((long)(m0 + br_ + srow) * 4096 + kb_));             \
    } } while (0)

#define STAGE_BX(buf, kt) do {                                                 \
    const long kb_ = (long)(kt) * 128 + swz16;                                 \
    _Pragma("unroll")                                                          \
    for (int j_ = 0; j_ < 2; ++j_) {                                           \
        const int br_ = w * 16 + j_ * 8;                                       \
        async_copy16(smem + (buf) * 65536 + 32768 + br_ * 128,                 \
                     gBx + ((long)(e0 + br_ + srow) * 4096 + kb_));            \
    } } while (0)

#define STAGE_BA(buf, kt) do {                                                 \
    const long kb_ = (long)(kt) * 128 + swz16;                                 \
    _Pragma("unroll")                                                          \
    for (int j_ = 0; j_ < 2; ++j_) {                                           \
        const int br_ = w * 16 + j_ * 8;                                       \
        async_copy16(smem + (buf) * 65536 + 49152 + br_ * 128,                 \
                     gBa + ((long)(e0 + br_ + srow) * 4096 + kb_));            \
    } } while (0)

#define PHASE_MID() do {                                                       \
    __builtin_amdgcn_s_barrier();                                              \
    asm volatile("s_waitcnt lgkmcnt(0)" ::: "memory");                         \
    __builtin_amdgcn_sched_barrier(0);                                         \
    __builtin_amdgcn_s_setprio(1); } while (0)

#define PHASE_END() do {                                                       \
    __builtin_amdgcn_s_setprio(0);                                             \
    __builtin_amdgcn_s_barrier(); } while (0)

    f32x4 accx[4][4];
    f32x4 acca[4][4];
#pragma unroll
    for (int i = 0; i < 4; ++i)
#pragma unroll
        for (int j = 0; j < 4; ++j) {
            accx[i][j] = (f32x4)(0.0f);
            acca[i][j] = (f32x4)(0.0f);
        }

    // prologue: stage kt=0 into buffer 0, full drain
    STAGE_A(0, 0, 0); STAGE_A(0, 0, 1); STAGE_BX(0, 0); STAGE_BA(0, 0);
    asm volatile("s_waitcnt vmcnt(0)" ::: "memory");
    __builtin_amdgcn_s_barrier();

    const int rL  = lane & 15;
    const int ch0 = ((0 + (lane >> 4)) ^ (lane & 7)) * 16;  // ks=0 chunk byte
    const int ch1 = ((4 + (lane >> 4)) ^ (lane & 7)) * 16;  // ks=1 chunk byte

    for (int kt = 0; kt < KTILES; ++kt) {
        const int c  = kt & 1;
        const int nb = 1 - c;
        char* sA  = smem + c * 65536;
        char* sBx = sA + 32768;
        char* sBa = sA + 49152;
        const bool pf = (kt < KTILES - 1);

        bf16x8 af[4], bf[4];

        // ---- phase 0: ks=0, gate x ----
#pragma unroll
        for (int i = 0; i < 4; ++i) {
            const int r = wm * 64 + i * 16 + rL;
            af[i] = *reinterpret_cast<const bf16x8*>(sA + r * 128 + ch0);
        }
#pragma unroll
        for (int j = 0; j < 4; ++j) {
            const int r = wn * 64 + j * 16 + rL;
            bf[j] = *reinterpret_cast<const bf16x8*>(sBx + r * 128 + ch0);
        }
        if (pf) STAGE_A(nb, kt + 1, 0);
        PHASE_MID();
#pragma unroll
        for (int i = 0; i < 4; ++i)
#pragma unroll
            for (int j = 0; j < 4; ++j)
                accx[i][j] = __builtin_amdgcn_mfma_f32_16x16x32_bf16(
                    af[i], bf[j], accx[i][j], 0, 0, 0);
        PHASE_END();

        // ---- phase 1: ks=0, gate a (reuse af) ----
#pragma unroll
        for (int j = 0; j < 4; ++j) {
            const int r = wn * 64 + j * 16 + rL;
            bf[j] = *reinterpret_cast<const bf16x8*>(sBa + r * 128 + ch0);
        }
        if (pf) STAGE_A(nb, kt + 1, 1);
        PHASE_MID();
#pragma unroll
        for (int i = 0; i < 4; ++i)
#pragma unroll
            for (int j = 0; j < 4; ++j)
                acca[i][j] = __builtin_amdgcn_mfma_f32_16x16x32_bf16(
                    af[i], bf[j], acca[i][j], 0, 0, 0);
        PHASE_END();

        // ---- phase 2: ks=1, gate x ----
#pragma unroll
        for (int i = 0; i < 4; ++i) {
            const int r = wm * 64 + i * 16 + rL;
            af[i] = *reinterpret_cast<const bf16x8*>(sA + r * 128 + ch1);
        }
#pragma unroll
        for (int j = 0; j < 4; ++j) {
            const int r = wn * 64 + j * 16 + rL;
            bf[j] = *reinterpret_cast<const bf16x8*>(sBx + r * 128 + ch1);
        }
        if (pf) STAGE_BX(nb, kt + 1);
        PHASE_MID();
#pragma unroll
        for (int i = 0; i < 4; ++i)
#pragma unroll
            for (int j = 0; j < 4; ++j)
                accx[i][j] = __builtin_amdgcn_mfma_f32_16x16x32_bf16(
                    af[i], bf[j], accx[i][j], 0, 0, 0);
        PHASE_END();

        // ---- phase 3: ks=1, gate a (reuse af) ----
#pragma unroll
        for (int j = 0; j < 4; ++j) {
            const int r = wn * 64 + j * 16 + rL;
            bf[j] = *reinterpret_cast<const bf16x8*>(sBa + r * 128 + ch1);
        }
        if (pf) STAGE_BA(nb, kt + 1);
        PHASE_MID();
#pragma unroll
        for (int i = 0; i < 4; ++i)
#pragma unroll
            for (int j = 0; j < 4; ++j)
                acca[i][j] = __builtin_amdgcn_mfma_f32_16x16x32_bf16(
                    af[i], bf[j], acca[i][j], 0, 0, 0);
        __builtin_amdgcn_s_setprio(0);
        // iteration boundary: next buffer must be fully staged before reads
        if (pf) asm volatile("s_waitcnt vmcnt(0)" ::: "memory");
        __builtin_amdgcn_s_barrier();
    }

#undef STAGE_A
#undef STAGE_BX
#undef STAGE_BA
#undef PHASE_MID
#undef PHASE_END

    // ---- epilogue: gates + a + normed_x ----
    const int rgrp = lane >> 4;
#pragma unroll
    for (int j = 0; j < 4; ++j) {
        const int e = e0 + wn * 64 + j * 16 + rL;
        const float bxv = bx[e];
        const float bav = ba[e];
        const float cvv = cv[e];
#pragma unroll
        for (int i = 0; i < 4; ++i) {
            const int mbase = m0 + wm * 64 + i * 16 + rgrp * 4;
#pragma unroll
            for (int r = 0; r < 4; ++r) {
                const int m = mbase + r;
                const float zx = accx[i][j][r] + bxv;
                const float za = acca[i][j][r] + bav;
                const float gx = 1.0f / (1.0f + __expf(-zx));
                const float ga = 1.0f / (1.0f + __expf(-za));
                const float la = cvv * ga;
                float a = __expf(la);
                float mult = sqrtf(fmaxf(1.0f - a * a, 0.0f));
                if (m < B_SZ) { a = 0.0f; mult = 1.0f; }  // s == 0 reset
                const long o = (long)m * D_DIM + e;
                const float xv = x32[o];
                abuf[o] = a;
                y[o] = xv * gx * mult;
            }
        }
    }
}

// ---------------- in-place scan over S: h = a*h + xn, y <- h -----------------
__global__ __launch_bounds__(64) void k_scan(
    const float* __restrict__ abuf,
    float* __restrict__ y,           // contains xn; overwritten with h states
    const float* __restrict__ h0,
    float* __restrict__ hn) {
    const int c = blockIdx.x * 64 + threadIdx.x;  // chain id, 0..16383
    float h = h0[c];

    float av0[16], xv0[16], av1[16], xv1[16];
    // prologue: load group 0
#pragma unroll
    for (int j = 0; j < 16; ++j) {
        const long o = (long)j * CHAINS + c;
        av0[j] = abuf[o];
        xv0[j] = y[o];
    }
    // 128 groups of 16 steps, ping-pong double-buffer (static indexing only)
    for (int g = 0; g < 128; g += 2) {
        const long base1 = ((long)(g + 1) * 16) * CHAINS + c;
        if (g + 1 < 128) {
#pragma unroll
            for (int j = 0; j < 16; ++j) {
                av1[j] = abuf[base1 + (long)j * CHAINS];
                xv1[j] = y[base1 + (long)j * CHAINS];
            }
        }
        const long base0 = ((long)g * 16) * CHAINS + c;
#pragma unroll
        for (int j = 0; j < 16; ++j) {
            h = fmaf(av0[j], h, xv0[j]);
            y[base0 + (long)j * CHAINS] = h;
        }
        const long base2 = ((long)(g + 2) * 16) * CHAINS + c;
        if (g + 2 < 128) {
#pragma unroll
            for (int j = 0; j < 16; ++j) {
                av0[j] = abuf[base2 + (long)j * CHAINS];
                xv0[j] = y[base2 + (long)j * CHAINS];
            }
        }
        if (g + 1 < 128) {
#pragma unroll
            for (int j = 0; j < 16; ++j) {
                h = fmaf(av1[j], h, xv1[j]);
                y[base1 + (long)j * CHAINS] = h;
            }
        }
    }
    hn[c] = h;
}

// ---------------- launch -----------------------------------------------------
extern "C" void kernel_launch(void* const* d_in, const int* in_sizes, int n_in,
                              void* d_out, int out_size, void* d_ws, size_t ws_size,
                              hipStream_t stream) {
    const float* x  = (const float*)d_in[0];
    const float* h0 = (const float*)d_in[1];
    const float* Wx = (const float*)d_in[2];
    const float* bx = (const float*)d_in[3];
    const float* Wa = (const float*)d_in[4];
    const float* ba = (const float*)d_in[5];
    const float* ap = (const float*)d_in[6];
    float* out = (float*)d_out;

    char* ws = (char*)d_ws;
    bf16*  xb   = (bf16*)(ws);
    bf16*  wxb  = (bf16*)(ws + 67108864L);
    bf16*  wab  = (bf16*)(ws + 75497472L);
    float* cv   = (float*)(ws + 83886080L);
    float* abuf = (float*)(ws + 83894272L);

    float* y  = out;                         // S*B*D
    float* hn = out + (long)M_DIM * D_DIM;   // B*D

    k_convert<<<dim3(2048), dim3(256), 0, stream>>>(
        (const float4*)x, (const float4*)Wx, (const float4*)Wa, xb, wxb, wab);
    k_cvec<<<dim3(8), dim3(256), 0, stream>>>(ap, cv);
    k_gemm<<<dim3(M_DIM / 256 * (D_DIM / 128)), dim3(512), 0, stream>>>(
        xb, wxb, wab, x, bx, ba, cv, abuf, y);
    k_scan<<<dim3(CHAINS / 64), dim3(64), 0, stream>>>(abuf, y, h0, hn);
}

// Round 3
// 483.378 us; speedup vs baseline: 1.0472x; 1.0058x over previous
//
#include <hip/hip_runtime.h>
#include <cstdint>

#define S_LEN 2048
#define B_SZ 8
#define D_DIM 2048
#define M_DIM (S_LEN * B_SZ)   // 16384 tokens
#define CHAINS (B_SZ * D_DIM)  // 16384 scan chains
#define BK 64
#define KTILES (D_DIM / BK)    // 32

typedef __bf16 bf16;
typedef bf16 bf16x8 __attribute__((ext_vector_type(8)));
typedef bf16 bf16x4 __attribute__((ext_vector_type(4)));
typedef float f32x4 __attribute__((ext_vector_type(4)));

// ---------------- async global->LDS (16B, wave-uniform LDS base + lane*16) ----
__device__ __forceinline__ void async_copy16(void* lds, const void* g) {
    __builtin_amdgcn_global_load_lds(
        (const __attribute__((address_space(1))) unsigned int*)g,
        (__attribute__((address_space(3))) unsigned int*)lds,
        16, 0, 0);
}

// ---------------- fp32 -> bf16 conversion of x, W_x, W_a ---------------------
__global__ void k_convert(const float4* __restrict__ x,
                          const float4* __restrict__ wx,
                          const float4* __restrict__ wa,
                          bf16* __restrict__ xb,
                          bf16* __restrict__ wxb,
                          bf16* __restrict__ wab) {
    const long NX4 = (long)M_DIM * D_DIM / 4;   // 8388608
    const long NW4 = (long)D_DIM * D_DIM / 4;   // 1048576
    const long total = NX4 + 2 * NW4;
    for (long i = (long)blockIdx.x * blockDim.x + threadIdx.x; i < total;
         i += (long)gridDim.x * blockDim.x) {
        const float4* s; bf16* d; long k;
        if (i < NX4)            { s = x;  d = xb;  k = i; }
        else if (i < NX4 + NW4) { s = wx; d = wxb; k = i - NX4; }
        else                    { s = wa; d = wab; k = i - NX4 - NW4; }
        float4 v = s[k];
        bf16x4 o;
        o[0] = (bf16)v.x; o[1] = (bf16)v.y; o[2] = (bf16)v.z; o[3] = (bf16)v.w;
        *reinterpret_cast<bf16x4*>(d + 4 * k) = o;
    }
}

// ---------------- cvec[e] = -C * softplus(a_param[e]) ------------------------
__global__ void k_cvec(const float* __restrict__ ap, float* __restrict__ cv) {
    int e = blockIdx.x * blockDim.x + threadIdx.x;
    if (e < D_DIM) {
        float v = ap[e];
        cv[e] = -8.0f * log1pf(expf(v));
    }
}

// ---------------- fused dual-GEMM + gate epilogue, 4-phase counted-vmcnt -----
// Tile: BM=256 x BN=128 x BK=64, 8 waves (4M x 2N), dbuf LDS 2x64KB.
// Per tile t: phases issue next-tile stages in order [Bx | A01 | A23 | Ba];
// waits: end-ph0 vmcnt(2), end-ph3 vmcnt(2) (never 0 in steady state).
__global__ __launch_bounds__(512, 2) void k_gemm(
    const bf16* __restrict__ xb,    // [M][D] bf16
    const bf16* __restrict__ wxb,   // [D][D] bf16 (row e, col d)
    const bf16* __restrict__ wab,   // [D][D] bf16
    const float* __restrict__ x32,  // original x fp32
    const float* __restrict__ bx,
    const float* __restrict__ ba,
    const float* __restrict__ cv,
    float* __restrict__ abuf,       // [M][D] fp32
    float* __restrict__ y)          // [M][D] fp32 (normed_x staged here)
{
    __shared__ __align__(16) char smem[131072];  // 2 x 64KB buffers

    const int tid  = threadIdx.x;
    const int lane = tid & 63;
    const int w    = tid >> 6;       // 8 waves
    const int wm   = w >> 1;         // 0..3 (64 rows each)
    const int wn   = w & 1;          // 0..1 (64 cols each)

    // XCD-bijective swizzle: 1024 wgs = 8 xcds x 128 contiguous
    const int orig = blockIdx.x;
    const int wgid = (orig & 7) * 128 + (orig >> 3);
    const int m0 = (wgid >> 4) * 256;   // 64 M-blocks
    const int e0 = (wgid & 15) * 128;   // 16 N-blocks

    // staging geometry: one instr = 1KB = 8 rows of 128B
    const int srow  = lane >> 3;               // 0..7
    const int swz16 = ((lane & 7) ^ srow) * 16;  // inverse-swizzled src chunk

    const char* gA  = (const char*)xb;
    const char* gBx = (const char*)wxb;
    const char* gBa = (const char*)wab;

#define STAGE_A(buf, kt, p) do {                                               \
    const long kb_ = (long)(kt) * 128 + swz16;                                 \
    _Pragma("unroll")                                                          \
    for (int j_ = 0; j_ < 2; ++j_) {                                           \
        const int br_ = w * 32 + ((p) * 2 + j_) * 8;                           \
        async_copy16(smem + (buf) * 65536 + br_ * 128,                         \
                     gA + ((long)(m0 + br_ + srow) * 4096 + kb_));             \
    } } while (0)

#define STAGE_BX(buf, kt) do {                                                 \
    const long kb_ = (long)(kt) * 128 + swz16;                                 \
    _Pragma("unroll")                                                          \
    for (int j_ = 0; j_ < 2; ++j_) {                                           \
        const int br_ = w * 16 + j_ * 8;                                       \
        async_copy16(smem + (buf) * 65536 + 32768 + br_ * 128,                 \
                     gBx + ((long)(e0 + br_ + srow) * 4096 + kb_));            \
    } } while (0)

#define STAGE_BA(buf, kt) do {                                                 \
    const long kb_ = (long)(kt) * 128 + swz16;                                 \
    _Pragma("unroll")                                                          \
    for (int j_ = 0; j_ < 2; ++j_) {                                           \
        const int br_ = w * 16 + j_ * 8;                                       \
        async_copy16(smem + (buf) * 65536 + 49152 + br_ * 128,                 \
                     gBa + ((long)(e0 + br_ + srow) * 4096 + kb_));            \
    } } while (0)

#define PHASE_MID() do {                                                       \
    __builtin_amdgcn_s_barrier();                                              \
    asm volatile("s_waitcnt lgkmcnt(0)" ::: "memory");                         \
    __builtin_amdgcn_sched_barrier(0);                                         \
    __builtin_amdgcn_s_setprio(1); } while (0)

    f32x4 accx[4][4];
    f32x4 acca[4][4];
#pragma unroll
    for (int i = 0; i < 4; ++i)
#pragma unroll
        for (int j = 0; j < 4; ++j) {
            accx[i][j] = (f32x4)(0.0f);
            acca[i][j] = (f32x4)(0.0f);
        }

    // prologue: stage kt=0 into buffer 0 in issue order [Bx, A01, A23, Ba],
    // then counted wait: oldest 6 (Bx + A) landed, Ba may stay in flight.
    STAGE_BX(0, 0); STAGE_A(0, 0, 0); STAGE_A(0, 0, 1); STAGE_BA(0, 0);
    asm volatile("s_waitcnt vmcnt(2)" ::: "memory");
    __builtin_amdgcn_s_barrier();

    const int rL  = lane & 15;
    const int ch0 = ((0 + (lane >> 4)) ^ (lane & 7)) * 16;  // ks=0 chunk byte
    const int ch1 = ((4 + (lane >> 4)) ^ (lane & 7)) * 16;  // ks=1 chunk byte

    for (int kt = 0; kt < KTILES; ++kt) {
        const int c  = kt & 1;
        const int nb = 1 - c;
        char* sA  = smem + c * 65536;
        char* sBx = sA + 32768;
        char* sBa = sA + 49152;
        const bool pf = (kt < KTILES - 1);

        bf16x8 af[4], bf[4];

        // ---- phase 0: ks=0, gate x ; stage Bx(t+1) ----
#pragma unroll
        for (int i = 0; i < 4; ++i) {
            const int r = wm * 64 + i * 16 + rL;
            af[i] = *reinterpret_cast<const bf16x8*>(sA + r * 128 + ch0);
        }
#pragma unroll
        for (int j = 0; j < 4; ++j) {
            const int r = wn * 64 + j * 16 + rL;
            bf[j] = *reinterpret_cast<const bf16x8*>(sBx + r * 128 + ch0);
        }
        if (pf) STAGE_BX(nb, kt + 1);
        PHASE_MID();
#pragma unroll
        for (int i = 0; i < 4; ++i)
#pragma unroll
            for (int j = 0; j < 4; ++j)
                accx[i][j] = __builtin_amdgcn_mfma_f32_16x16x32_bf16(
                    af[i], bf[j], accx[i][j], 0, 0, 0);
        __builtin_amdgcn_s_setprio(0);
        // make this tile's Ba (2 oldest outstanding after it) visible for ph1
        if (pf) asm volatile("s_waitcnt vmcnt(2)" ::: "memory");
        else    asm volatile("s_waitcnt vmcnt(0)" ::: "memory");
        __builtin_amdgcn_s_barrier();

        // ---- phase 1: ks=0, gate a (reuse af) ; stage A01(t+1) ----
#pragma unroll
        for (int j = 0; j < 4; ++j) {
            const int r = wn * 64 + j * 16 + rL;
            bf[j] = *reinterpret_cast<const bf16x8*>(sBa + r * 128 + ch0);
        }
        if (pf) STAGE_A(nb, kt + 1, 0);
        PHASE_MID();
#pragma unroll
        for (int i = 0; i < 4; ++i)
#pragma unroll
            for (int j = 0; j < 4; ++j)
                acca[i][j] = __builtin_amdgcn_mfma_f32_16x16x32_bf16(
                    af[i], bf[j], acca[i][j], 0, 0, 0);
        __builtin_amdgcn_s_setprio(0);
        __builtin_amdgcn_s_barrier();

        // ---- phase 2: ks=1, gate x ; stage A23(t+1) ----
#pragma unroll
        for (int i = 0; i < 4; ++i) {
            const int r = wm * 64 + i * 16 + rL;
            af[i] = *reinterpret_cast<const bf16x8*>(sA + r * 128 + ch1);
        }
#pragma unroll
        for (int j = 0; j < 4; ++j) {
            const int r = wn * 64 + j * 16 + rL;
            bf[j] = *reinterpret_cast<const bf16x8*>(sBx + r * 128 + ch1);
        }
        if (pf) STAGE_A(nb, kt + 1, 1);
        PHASE_MID();
#pragma unroll
        for (int i = 0; i < 4; ++i)
#pragma unroll
            for (int j = 0; j < 4; ++j)
                accx[i][j] = __builtin_amdgcn_mfma_f32_16x16x32_bf16(
                    af[i], bf[j], accx[i][j], 0, 0, 0);
        __builtin_amdgcn_s_setprio(0);
        __builtin_amdgcn_s_barrier();

        // ---- phase 3: ks=1, gate a (reuse af) ; stage Ba(t+1) ----
#pragma unroll
        for (int j = 0; j < 4; ++j) {
            const int r = wn * 64 + j * 16 + rL;
            bf[j] = *reinterpret_cast<const bf16x8*>(sBa + r * 128 + ch1);
        }
        if (pf) STAGE_BA(nb, kt + 1);
        PHASE_MID();
#pragma unroll
        for (int i = 0; i < 4; ++i)
#pragma unroll
            for (int j = 0; j < 4; ++j)
                acca[i][j] = __builtin_amdgcn_mfma_f32_16x16x32_bf16(
                    af[i], bf[j], acca[i][j], 0, 0, 0);
        __builtin_amdgcn_s_setprio(0);
        // boundary: oldest 6 of next tile (Bx + A) must land; Ba stays in flight
        if (pf) asm volatile("s_waitcnt vmcnt(2)" ::: "memory");
        __builtin_amdgcn_s_barrier();
    }

#undef STAGE_A
#undef STAGE_BX
#undef STAGE_BA
#undef PHASE_MID

    // ---- epilogue: gates + a + normed_x ----
    const int rgrp = lane >> 4;
#pragma unroll
    for (int j = 0; j < 4; ++j) {
        const int e = e0 + wn * 64 + j * 16 + rL;
        const float bxv = bx[e];
        const float bav = ba[e];
        const float cvv = cv[e];
#pragma unroll
        for (int i = 0; i < 4; ++i) {
            const int mbase = m0 + wm * 64 + i * 16 + rgrp * 4;
#pragma unroll
            for (int r = 0; r < 4; ++r) {
                const int m = mbase + r;
                const float zx = accx[i][j][r] + bxv;
                const float za = acca[i][j][r] + bav;
                const float gx = 1.0f / (1.0f + __expf(-zx));
                const float ga = 1.0f / (1.0f + __expf(-za));
                const float la = cvv * ga;
                float a = __expf(la);
                float mult = sqrtf(fmaxf(1.0f - a * a, 0.0f));
                if (m < B_SZ) { a = 0.0f; mult = 1.0f; }  // s == 0 reset
                const long o = (long)m * D_DIM + e;
                const float xv = x32[o];
                abuf[o] = a;
                y[o] = xv * gx * mult;
            }
        }
    }
}

// ---------------- in-place scan over S: h = a*h + xn, y <- h -----------------
__global__ __launch_bounds__(64) void k_scan(
    const float* __restrict__ abuf,
    float* __restrict__ y,           // contains xn; overwritten with h states
    const float* __restrict__ h0,
    float* __restrict__ hn) {
    const int c = blockIdx.x * 64 + threadIdx.x;  // chain id, 0..16383
    float h = h0[c];

    float av0[16], xv0[16], av1[16], xv1[16];
    // prologue: load group 0
#pragma unroll
    for (int j = 0; j < 16; ++j) {
        const long o = (long)j * CHAINS + c;
        av0[j] = abuf[o];
        xv0[j] = y[o];
    }
    // 128 groups of 16 steps, ping-pong double-buffer (static indexing only)
    for (int g = 0; g < 128; g += 2) {
        const long base1 = ((long)(g + 1) * 16) * CHAINS + c;
        if (g + 1 < 128) {
#pragma unroll
            for (int j = 0; j < 16; ++j) {
                av1[j] = abuf[base1 + (long)j * CHAINS];
                xv1[j] = y[base1 + (long)j * CHAINS];
            }
        }
        const long base0 = ((long)g * 16) * CHAINS + c;
#pragma unroll
        for (int j = 0; j < 16; ++j) {
            h = fmaf(av0[j], h, xv0[j]);
            y[base0 + (long)j * CHAINS] = h;
        }
        const long base2 = ((long)(g + 2) * 16) * CHAINS + c;
        if (g + 2 < 128) {
#pragma unroll
            for (int j = 0; j < 16; ++j) {
                av0[j] = abuf[base2 + (long)j * CHAINS];
                xv0[j] = y[base2 + (long)j * CHAINS];
            }
        }
        if (g + 1 < 128) {
#pragma unroll
            for (int j = 0; j < 16; ++j) {
                h = fmaf(av1[j], h, xv1[j]);
                y[base1 + (long)j * CHAINS] = h;
            }
        }
    }
    hn[c] = h;
}

// ---------------- launch -----------------------------------------------------
extern "C" void kernel_launch(void* const* d_in, const int* in_sizes, int n_in,
                              void* d_out, int out_size, void* d_ws, size_t ws_size,
                              hipStream_t stream) {
    const float* x  = (const float*)d_in[0];
    const float* h0 = (const float*)d_in[1];
    const float* Wx = (const float*)d_in[2];
    const float* bx = (const float*)d_in[3];
    const float* Wa = (const float*)d_in[4];
    const float* ba = (const float*)d_in[5];
    const float* ap = (const float*)d_in[6];
    float* out = (float*)d_out;

    char* ws = (char*)d_ws;
    bf16*  xb   = (bf16*)(ws);
    bf16*  wxb  = (bf16*)(ws + 67108864L);
    bf16*  wab  = (bf16*)(ws + 75497472L);
    float* cv   = (float*)(ws + 83886080L);
    float* abuf = (float*)(ws + 83894272L);

    float* y  = out;                         // S*B*D
    float* hn = out + (long)M_DIM * D_DIM;   // B*D

    k_convert<<<dim3(2048), dim3(256), 0, stream>>>(
        (const float4*)x, (const float4*)Wx, (const float4*)Wa, xb, wxb, wab);
    k_cvec<<<dim3(8), dim3(256), 0, stream>>>(ap, cv);
    k_gemm<<<dim3(M_DIM / 256 * (D_DIM / 128)), dim3(512), 0, stream>>>(
        xb, wxb, wab, x, bx, ba, cv, abuf, y);
    k_scan<<<dim3(CHAINS / 64), dim3(64), 0, stream>>>(abuf, y, h0, hn);
}